// Round 2
// baseline (1619.705 us; speedup 1.0000x reference)
//
#include <hip/hip_runtime.h>
#include <math.h>

// Problem dims (fixed by reference)
#define B_   16
#define DEC_ 2048
#define ENC_ 2048
#define H_   1024

typedef __attribute__((ext_vector_type(8))) short short8;
typedef __attribute__((ext_vector_type(4))) float f32x4;

// round-to-nearest-even fp32 -> bf16 bits
__device__ __forceinline__ unsigned short bf16_rn_bits(float x) {
    unsigned u = __builtin_bit_cast(unsigned, x);
    unsigned r = u + 0x7FFFu + ((u >> 16) & 1u);
    return (unsigned short)(r >> 16);
}

// split fp32 into hi (bf16 RN) + lo (bf16 RN of residual)
__device__ __forceinline__ void bf16_split(float x, short& hi, short& lo) {
    unsigned u = __builtin_bit_cast(unsigned, x);
    unsigned hr = (u + 0x7FFFu + ((u >> 16) & 1u)) & 0xFFFF0000u;
    hi = (short)(hr >> 16);
    float hf = __builtin_bit_cast(float, hr);
    float l = x - hf;   // exact (Sterbenz-like: hi has x's top bits)
    lo = (short)bf16_rn_bits(l);
}

// ---------------------------------------------------------------------------
// Kernel 1: scores[b,d,e] = sum_h dec[b,d,h] * enc[b,e,h]
// Split-bf16: D = Dh+Dl, E = Eh+El; S = Dh*Eh + Dh*El + Dl*Eh (drop Dl*El)
// 128x128 tile, BK=32, 256 threads (4 waves, 2x2 of 64x64 per-wave tiles)
// ---------------------------------------------------------------------------
__global__ __launch_bounds__(256) void scores_kernel(
    const float* __restrict__ dec, const float* __restrict__ enc,
    float* __restrict__ attn)
{
    __shared__ short Ahi[128 * 32];
    __shared__ short Alo[128 * 32];
    __shared__ short Bhi[128 * 32];
    __shared__ short Blo[128 * 32];

    const int t    = threadIdx.x;
    const int lane = t & 63;
    const int w    = t >> 6;
    const int wr   = w >> 1;        // 0..1
    const int wc   = w & 1;         // 0..1
    const int b    = blockIdx.z;
    const int brow = blockIdx.y * 128;   // decoder rows
    const int bcol = blockIdx.x * 128;   // encoder rows (score cols)

    const float* Abase = dec + ((size_t)b * DEC_ + brow) * H_;
    const float* Bbase = enc + ((size_t)b * ENC_ + bcol) * H_;

    f32x4 acc[4][4];
    #pragma unroll
    for (int i = 0; i < 4; ++i)
        #pragma unroll
        for (int j = 0; j < 4; ++j)
            acc[i][j] = (f32x4){0.f, 0.f, 0.f, 0.f};

    const int lr = lane & 15;   // row-in-fragment
    const int kg = lane >> 4;   // k-octet group 0..3

    const int srow = t >> 2;        // staging row (0..63), +64 on 2nd iter
    const int skk  = (t & 3) * 8;   // staging k offset (8 fp32 per thread)

    for (int k0 = 0; k0 < H_; k0 += 32) {
        // ---- stage fp32 -> split bf16 into swizzled LDS ----
        #pragma unroll
        for (int io = 0; io < 2; ++io) {
            const int row = srow + io * 64;
            const float* ga = Abase + (size_t)row * H_ + (k0 + skk);
            const float* gb = Bbase + (size_t)row * H_ + (k0 + skk);
            float4 a0 = *(const float4*)ga;
            float4 a1 = *(const float4*)(ga + 4);
            float4 b0 = *(const float4*)gb;
            float4 b1 = *(const float4*)(gb + 4);
            float av[8] = {a0.x, a0.y, a0.z, a0.w, a1.x, a1.y, a1.z, a1.w};
            float bv[8] = {b0.x, b0.y, b0.z, b0.w, b1.x, b1.y, b1.z, b1.w};
            short8 ah, al, bh, bl;
            #pragma unroll
            for (int j = 0; j < 8; ++j) {
                short h, l;
                bf16_split(av[j], h, l); ah[j] = h; al[j] = l;
                bf16_split(bv[j], h, l); bh[j] = h; bl[j] = l;
            }
            const int c    = (t & 3) ^ ((row >> 1) & 3);  // XOR swizzle (16B chunks)
            const int base = row * 32 + c * 8;
            *(short8*)&Ahi[base] = ah;
            *(short8*)&Alo[base] = al;
            *(short8*)&Bhi[base] = bh;
            *(short8*)&Blo[base] = bl;
        }
        __syncthreads();

        // ---- fragment loads (A: m=lane&15, k=(lane>>4)*8+i; B symmetric) ----
        short8 afh[4], afl[4], bfh[4], bfl[4];
        #pragma unroll
        for (int mf = 0; mf < 4; ++mf) {
            const int row  = wr * 64 + mf * 16 + lr;
            const int base = row * 32 + (kg ^ ((row >> 1) & 3)) * 8;
            afh[mf] = *(const short8*)&Ahi[base];
            afl[mf] = *(const short8*)&Alo[base];
        }
        #pragma unroll
        for (int nf = 0; nf < 4; ++nf) {
            const int row  = wc * 64 + nf * 16 + lr;
            const int base = row * 32 + (kg ^ ((row >> 1) & 3)) * 8;
            bfh[nf] = *(const short8*)&Bhi[base];
            bfl[nf] = *(const short8*)&Blo[base];
        }

        #pragma unroll
        for (int mf = 0; mf < 4; ++mf)
            #pragma unroll
            for (int nf = 0; nf < 4; ++nf) {
                acc[mf][nf] = __builtin_amdgcn_mfma_f32_16x16x32_bf16(afh[mf], bfh[nf], acc[mf][nf], 0, 0, 0);
                acc[mf][nf] = __builtin_amdgcn_mfma_f32_16x16x32_bf16(afh[mf], bfl[nf], acc[mf][nf], 0, 0, 0);
                acc[mf][nf] = __builtin_amdgcn_mfma_f32_16x16x32_bf16(afl[mf], bfh[nf], acc[mf][nf], 0, 0, 0);
            }
        __syncthreads();
    }

    // ---- epilogue: C row=(lane>>4)*4+j, col=lane&15 ----
    float* out = attn + (size_t)b * DEC_ * ENC_;
    #pragma unroll
    for (int mf = 0; mf < 4; ++mf) {
        #pragma unroll
        for (int nf = 0; nf < 4; ++nf) {
            const int e = bcol + wc * 64 + nf * 16 + lr;
            #pragma unroll
            for (int j = 0; j < 4; ++j) {
                const int d = brow + wr * 64 + mf * 16 + kg * 4 + j;
                out[(size_t)d * ENC_ + e] = acc[mf][nf][j];
            }
        }
    }
}

// ---------------------------------------------------------------------------
// Kernel 2: in-place masked row softmax over attn[b,d,:]
// mask[b,e] = (enc[b,e,0] == 0)  -> prob 0
// One 256-thread block per row; 8 elements per thread.
// ---------------------------------------------------------------------------
__global__ __launch_bounds__(256) void softmax_kernel(
    const float* __restrict__ enc, float* __restrict__ attn)
{
    const int d = blockIdx.x;
    const int b = blockIdx.y;
    float* p = attn + ((size_t)b * DEC_ + d) * ENC_;
    const float* e0 = enc + (size_t)b * ENC_ * H_;

    const int t    = threadIdx.x;
    const int lane = t & 63;
    const int w    = t >> 6;

    float v[8];
    {
        float4 s0 = *(const float4*)(p + t * 8);
        float4 s1 = *(const float4*)(p + t * 8 + 4);
        v[0] = s0.x; v[1] = s0.y; v[2] = s0.z; v[3] = s0.w;
        v[4] = s1.x; v[5] = s1.y; v[6] = s1.z; v[7] = s1.w;
    }
    float lmax = -INFINITY;
    #pragma unroll
    for (int j = 0; j < 8; ++j) {
        const int e = t * 8 + j;
        const bool msk = (e0[(size_t)e * H_] == 0.0f);
        v[j] = msk ? -INFINITY : v[j];
        lmax = fmaxf(lmax, v[j]);
    }

    __shared__ float redmax[4];
    __shared__ float redsum[4];

    #pragma unroll
    for (int off = 32; off > 0; off >>= 1)
        lmax = fmaxf(lmax, __shfl_xor(lmax, off));
    if (lane == 0) redmax[w] = lmax;
    __syncthreads();
    const float bmax = fmaxf(fmaxf(redmax[0], redmax[1]), fmaxf(redmax[2], redmax[3]));

    float lsum = 0.f;
    #pragma unroll
    for (int j = 0; j < 8; ++j) {
        const float ev = (v[j] == -INFINITY) ? 0.f : __expf(v[j] - bmax);
        v[j] = ev;
        lsum += ev;
    }
    #pragma unroll
    for (int off = 32; off > 0; off >>= 1)
        lsum += __shfl_xor(lsum, off);
    if (lane == 0) redsum[w] = lsum;
    __syncthreads();
    const float inv = 1.f / (redsum[0] + redsum[1] + redsum[2] + redsum[3]);

    float4 o0 = {v[0] * inv, v[1] * inv, v[2] * inv, v[3] * inv};
    float4 o1 = {v[4] * inv, v[5] * inv, v[6] * inv, v[7] * inv};
    *(float4*)(p + t * 8)     = o0;
    *(float4*)(p + t * 8 + 4) = o1;
}

// ---------------------------------------------------------------------------
// Kernel 3: context[b,d,h] = sum_e attn[b,d,e] * enc[b,e,h]   (plain bf16)
// A = attn [d][e] row-major (k-contig); B = enc [e][h] (k-strided: transpose
// during staging via per-lane coalesced column loads).
// ---------------------------------------------------------------------------
__global__ __launch_bounds__(256) void context_kernel(
    const float* __restrict__ attn, const float* __restrict__ enc,
    float* __restrict__ ctx)
{
    __shared__ short Abf[128 * 32];
    __shared__ short Bbf[128 * 32];

    const int t    = threadIdx.x;
    const int lane = t & 63;
    const int w    = t >> 6;
    const int wr   = w >> 1;
    const int wc   = w & 1;
    const int b    = blockIdx.z;
    const int brow = blockIdx.y * 128;   // decoder rows
    const int hcol = blockIdx.x * 128;   // H cols

    const float* Pbase = attn + ((size_t)b * DEC_ + brow) * ENC_;
    const float* Ebase = enc + (size_t)b * ENC_ * H_ + hcol;

    f32x4 acc[4][4];
    #pragma unroll
    for (int i = 0; i < 4; ++i)
        #pragma unroll
        for (int j = 0; j < 4; ++j)
            acc[i][j] = (f32x4){0.f, 0.f, 0.f, 0.f};

    const int lr = lane & 15;
    const int kg = lane >> 4;

    const int srow = t >> 2;
    const int skk  = (t & 3) * 8;
    const int bn   = t & 127;         // B-stage: output col (h)
    const int bkh  = (t >> 7) * 16;   // B-stage: k half (0 or 16)

    for (int k0 = 0; k0 < ENC_; k0 += 32) {
        // ---- A stage: P rows (k-contiguous), single bf16 ----
        #pragma unroll
        for (int io = 0; io < 2; ++io) {
            const int row = srow + io * 64;
            const float* g = Pbase + (size_t)row * ENC_ + (k0 + skk);
            float4 p0 = *(const float4*)g;
            float4 p1 = *(const float4*)(g + 4);
            float pv[8] = {p0.x, p0.y, p0.z, p0.w, p1.x, p1.y, p1.z, p1.w};
            short8 ab;
            #pragma unroll
            for (int j = 0; j < 8; ++j) ab[j] = (short)bf16_rn_bits(pv[j]);
            const int c = (t & 3) ^ ((row >> 1) & 3);
            *(short8*)&Abf[row * 32 + c * 8] = ab;
        }
        // ---- B stage: transpose E tile -> Bbf[n][k] (lane-coalesced per j) ----
        {
            const float* g = Ebase + (size_t)(k0 + bkh) * H_ + bn;
            short sv[16];
            #pragma unroll
            for (int j = 0; j < 16; ++j)
                sv[j] = (short)bf16_rn_bits(g[(size_t)j * H_]);
            short8 s0, s1;
            #pragma unroll
            for (int j = 0; j < 8; ++j) { s0[j] = sv[j]; s1[j] = sv[j + 8]; }
            const int sw = (bn >> 1) & 3;
            const int c0 = bkh >> 3;       // 0 or 2
            *(short8*)&Bbf[bn * 32 + (c0 ^ sw) * 8]       = s0;
            *(short8*)&Bbf[bn * 32 + ((c0 + 1) ^ sw) * 8] = s1;
        }
        __syncthreads();

        short8 af[4], bf[4];
        #pragma unroll
        for (int mf = 0; mf < 4; ++mf) {
            const int row = wr * 64 + mf * 16 + lr;
            af[mf] = *(const short8*)&Abf[row * 32 + (kg ^ ((row >> 1) & 3)) * 8];
        }
        #pragma unroll
        for (int nf = 0; nf < 4; ++nf) {
            const int row = wc * 64 + nf * 16 + lr;
            bf[nf] = *(const short8*)&Bbf[row * 32 + (kg ^ ((row >> 1) & 3)) * 8];
        }
        #pragma unroll
        for (int mf = 0; mf < 4; ++mf)
            #pragma unroll
            for (int nf = 0; nf < 4; ++nf)
                acc[mf][nf] = __builtin_amdgcn_mfma_f32_16x16x32_bf16(af[mf], bf[nf], acc[mf][nf], 0, 0, 0);
        __syncthreads();
    }

    float* out = ctx + (size_t)b * DEC_ * H_;
    #pragma unroll
    for (int mf = 0; mf < 4; ++mf) {
        #pragma unroll
        for (int nf = 0; nf < 4; ++nf) {
            const int h = hcol + wc * 64 + nf * 16 + lr;
            #pragma unroll
            for (int j = 0; j < 4; ++j) {
                const int d = brow + wr * 64 + mf * 16 + kg * 4 + j;
                out[(size_t)d * H_ + h] = acc[mf][nf][j];
            }
        }
    }
}

// ---------------------------------------------------------------------------
extern "C" void kernel_launch(void* const* d_in, const int* in_sizes, int n_in,
                              void* d_out, int out_size, void* d_ws, size_t ws_size,
                              hipStream_t stream)
{
    (void)in_sizes; (void)n_in; (void)d_ws; (void)ws_size; (void)out_size;

    const float* dec = (const float*)d_in[0];
    const float* enc = (const float*)d_in[1];

    float* ctx  = (float*)d_out;                                   // (B,DEC,H)
    float* attn = (float*)d_out + (size_t)B_ * DEC_ * H_;          // (B,DEC,ENC)

    // 1) raw scores into attn region
    scores_kernel<<<dim3(ENC_ / 128, DEC_ / 128, B_), 256, 0, stream>>>(dec, enc, attn);
    // 2) masked softmax in place
    softmax_kernel<<<dim3(DEC_, B_), 256, 0, stream>>>(enc, attn);
    // 3) context = P @ E
    context_kernel<<<dim3(H_ / 128, DEC_ / 128, B_), 256, 0, stream>>>(attn, enc, ctx);
}